// Round 6
// baseline (311.009 us; speedup 1.0000x reference)
//
#include <hip/hip_runtime.h>
#include <math.h>

#define B_ROWS 131072
#define D_DIM  1024
#define E_EXP  64
#define MARGIN 4e-3f

typedef _Float16 f16;
typedef _Float16 f16x8 __attribute__((ext_vector_type(8)));
typedef float    f32x4 __attribute__((ext_vector_type(4)));

// ---------- helpers ----------

__device__ __forceinline__ float softplus_f(float t) {
  return (t > 20.0f) ? t : log1pf(expf(t));
}
__device__ __forceinline__ float ndtr_f(float z) {
  return 0.5f * erfcf(-z * 0.70710678118654752f);
}
__device__ __forceinline__ void argmax64(float& v, int& vi) {
  #pragma unroll
  for (int off = 32; off > 0; off >>= 1) {
    float ov = __shfl_xor(v, off, 64);
    int   oi = __shfl_xor(vi, off, 64);
    if (ov > v || (ov == v && oi < vi)) { v = ov; vi = oi; }
  }
}
__device__ __forceinline__ float sum64(float v) {
  #pragma unroll
  for (int off = 32; off > 0; off >>= 1) v += __shfl_xor(v, off, 64);
  return v;
}

// full-64-lane (lane==expert) row epilogue, used by fixup only
__device__ __forceinline__ void row_epilogue_exact(
    int row, int lane, float clean, float sd, float l,
    float* __restrict__ gates_buf, float* __restrict__ logits_buf,
    float& load_acc, float& imp_acc, float& z_acc)
{
  float v1 = l; int i1 = lane; argmax64(v1, i1);
  float v2 = (lane == i1) ? -INFINITY : l; int i2 = lane; argmax64(v2, i2);
  float v3 = (lane == i1 || lane == i2) ? -INFINITY : l; int i3 = lane; argmax64(v3, i3);
  (void)i3;
  const float e21 = expf(v2 - v1);
  const float g1  = 1.0f / (1.0f + e21);
  const float g2  = e21 * g1;
  const float gv  = (lane == i1) ? g1 : ((lane == i2) ? g2 : 0.0f);
  gates_buf [(size_t)row * E_EXP + lane] = gv;
  logits_buf[(size_t)row * E_EXP + lane] = l;
  const float ssum = sum64(expf(l - v1));
  z_acc += v1 + logf(ssum);
  const float thr = (l > v3) ? v3 : v2;
  load_acc += ndtr_f((clean - thr) / sd);
  imp_acc  += gv;
}

// ---------- kernels ----------

// W^T f16 via coalesced LDS transpose; block 0 also zero-inits the accumulators.
__global__ __launch_bounds__(256) void prep_wt(
    const float* __restrict__ wg, const float* __restrict__ wn, f16* __restrict__ wt,
    float* load_o, float* imp_o, float* zsum, int* flagcnt) {
  if (blockIdx.x == 0) {
    const int t = threadIdx.x;
    if (t < 64) { load_o[t] = 0.0f; imp_o[t] = 0.0f; }
    if (t == 64) zsum[0] = 0.0f;
    if (t == 65) flagcnt[0] = 0;
  }
  __shared__ float tile[64][65];
  const int m  = blockIdx.x >> 4;       // 0 gate, 1 noise
  const int kt = blockIdx.x & 15;
  const int k0 = kt * 64;
  const float* src = m ? wn : wg;
  const int c = threadIdx.x & 63;
  const int r0 = threadIdx.x >> 6;
  #pragma unroll
  for (int r = r0; r < 64; r += 4)
    tile[r][c] = src[(size_t)(k0 + r) * 64 + c];   // coalesced read
  __syncthreads();
  const int j = threadIdx.x & 63;
  #pragma unroll
  for (int col = r0; col < 64; col += 4)
    wt[(size_t)(m * 64 + col) * 1024 + k0 + j] = (f16)tile[j][col];  // coalesced write
}

// Fused f16-MFMA GEMM + noisy-top-k epilogue. NO LDS staging, NO k-loop barriers:
// B (256 KB) is L2-resident; each wave loads its B frags straight to registers.
// Block: 4 waves x 32 rows = 128 rows. Wave: 32 rows x 128 cols (64 gate + 64 noise).
__global__ __launch_bounds__(256, 2) void gemm_fused(
    const float* __restrict__ x, const f16* __restrict__ wt,
    const float* __restrict__ eps,
    float* __restrict__ gates_buf, float* __restrict__ logits_buf,
    float* __restrict__ load_o, float* __restrict__ imp_o, float* __restrict__ zsum,
    int* __restrict__ flagcnt, int* __restrict__ flaglist)
{
  __shared__ float red[520];           // block reduction scratch only

  const int tid  = threadIdx.x;
  const int lane = tid & 63;
  const int wid  = tid >> 6;
  const int l15  = lane & 15;
  const int l4   = lane >> 4;
  const size_t rowbase = (size_t)blockIdx.x * 128 + wid * 32;

  // B frag base: wt[(et*16 + l15)][kc*64 + kl*32 + l4*8 ..+8]
  const f16* wb = wt + (size_t)l15 * 1024 + l4 * 8;

  // A: lane covers rows (rowbase + rt*16 + l15), k = l4*8..
  const float* xp0 = x + (rowbase +  0 + l15) * D_DIM + l4 * 8;
  const float* xp1 = x + (rowbase + 16 + l15) * D_DIM + l4 * 8;

  f32x4 acc[2][8];
  #pragma unroll
  for (int rt = 0; rt < 2; ++rt)
    #pragma unroll
    for (int et = 0; et < 8; ++et) acc[rt][et] = (f32x4)0.0f;

  float4 xa[8];   // xa[kl*4 + rt*2 + h]
#define LOAD_A(kc) do {                                                  \
    _Pragma("unroll")                                                    \
    for (int kl = 0; kl < 2; ++kl) {                                     \
      xa[kl*4 + 0] = *(const float4*)(xp0 + (kc)*64 + kl*32 + 0);        \
      xa[kl*4 + 1] = *(const float4*)(xp0 + (kc)*64 + kl*32 + 4);        \
      xa[kl*4 + 2] = *(const float4*)(xp1 + (kc)*64 + kl*32 + 0);        \
      xa[kl*4 + 3] = *(const float4*)(xp1 + (kc)*64 + kl*32 + 4);        \
    }                                                                    \
  } while (0)

  LOAD_A(0);

  #pragma unroll 1
  for (int kc = 0; kc < 16; ++kc) {
    // B loads for this chunk (L2-hit, issued first so they fly during cvt)
    f16x8 b[8][2];
    #pragma unroll
    for (int et = 0; et < 8; ++et) {
      #pragma unroll
      for (int kl = 0; kl < 2; ++kl)
        b[et][kl] = *(const f16x8*)(wb + (size_t)et * 16384 + kc * 64 + kl * 32);
    }

    // convert A(kc) -> f16 frags
    f16x8 af[2][2];   // [kl][rt]
    #pragma unroll
    for (int kl = 0; kl < 2; ++kl)
      #pragma unroll
      for (int rt = 0; rt < 2; ++rt) {
        #pragma unroll
        for (int h = 0; h < 2; ++h) {
          const float4 v = xa[kl*4 + rt*2 + h];
          af[kl][rt][h*4 + 0] = (f16)v.x;
          af[kl][rt][h*4 + 1] = (f16)v.y;
          af[kl][rt][h*4 + 2] = (f16)v.z;
          af[kl][rt][h*4 + 3] = (f16)v.w;
        }
      }

    // prefetch next chunk's A (the HBM stream — keep it always in flight)
    if (kc < 15) LOAD_A(kc + 1);

    // MFMA: 2 kl x 8 et x 2 rt
    #pragma unroll
    for (int kl = 0; kl < 2; ++kl) {
      #pragma unroll
      for (int et = 0; et < 8; ++et) {
        acc[0][et] = __builtin_amdgcn_mfma_f32_16x16x32_f16(af[kl][0], b[et][kl], acc[0][et], 0, 0, 0);
        acc[1][et] = __builtin_amdgcn_mfma_f32_16x16x32_f16(af[kl][1], b[et][kl], acc[1][et], 0, 0, 0);
      }
    }
  }
#undef LOAD_A

  // ---- fused epilogue: acc[rt][0..3] = clean, acc[rt][4..7] = sdraw ----
  float load_acc[4] = {0.f, 0.f, 0.f, 0.f};
  float imp_acc[4]  = {0.f, 0.f, 0.f, 0.f};
  float z_acc = 0.f;

  #pragma unroll
  for (int rt = 0; rt < 2; ++rt) {
    #pragma unroll
    for (int rg = 0; rg < 4; ++rg) {
      const size_t row = rowbase + rt * 16 + l4 * 4 + rg;
      float cl[4], sd[4], lg[4];
      #pragma unroll
      for (int j = 0; j < 4; ++j) {
        cl[j] = acc[rt][j][rg];
        sd[j] = softplus_f(acc[rt][4 + j][rg]) + 0.01f;
        const float ev = eps[row * E_EXP + j * 16 + l15];
        lg[j] = fmaf(ev, sd[j], cl[j]);
      }
      // top-1 over the row (16 lanes x 4 local)
      float v = lg[0]; int c = l15;
      #pragma unroll
      for (int j = 1; j < 4; ++j) {
        const int cj = j * 16 + l15;
        if (lg[j] > v || (lg[j] == v && cj < c)) { v = lg[j]; c = cj; }
      }
      #pragma unroll
      for (int off = 1; off < 16; off <<= 1) {
        const float ov = __shfl_xor(v, off, 64);
        const int   oc = __shfl_xor(c, off, 64);
        if (ov > v || (ov == v && oc < c)) { v = ov; c = oc; }
      }
      const float v1 = v; const int i1 = c;
      // top-2
      v = -INFINITY; c = 1 << 30;
      #pragma unroll
      for (int j = 0; j < 4; ++j) {
        const int cj = j * 16 + l15;
        if (cj != i1 && (lg[j] > v || (lg[j] == v && cj < c))) { v = lg[j]; c = cj; }
      }
      #pragma unroll
      for (int off = 1; off < 16; off <<= 1) {
        const float ov = __shfl_xor(v, off, 64);
        const int   oc = __shfl_xor(c, off, 64);
        if (ov > v || (ov == v && oc < c)) { v = ov; c = oc; }
      }
      const float v2 = v; const int i2 = c;
      // top-3 (value only)
      float v3 = -INFINITY;
      #pragma unroll
      for (int j = 0; j < 4; ++j) {
        const int cj = j * 16 + l15;
        if (cj != i1 && cj != i2) v3 = fmaxf(v3, lg[j]);
      }
      #pragma unroll
      for (int off = 1; off < 16; off <<= 1) v3 = fmaxf(v3, __shfl_xor(v3, off, 64));

      if (v2 - v3 >= MARGIN) {
        const float e21 = expf(v2 - v1);
        const float g1  = 1.0f / (1.0f + e21);
        const float g2  = e21 * g1;
        float s = 0.f;
        #pragma unroll
        for (int j = 0; j < 4; ++j) s += expf(lg[j] - v1);
        #pragma unroll
        for (int off = 1; off < 16; off <<= 1) s += __shfl_xor(s, off, 64);
        if (l15 == 0) z_acc += v1 + logf(s);
        #pragma unroll
        for (int j = 0; j < 4; ++j) {
          const int cj = j * 16 + l15;
          const float gv = (cj == i1) ? g1 : ((cj == i2) ? g2 : 0.0f);
          gates_buf [row * E_EXP + cj] = gv;
          logits_buf[row * E_EXP + cj] = lg[j];
          imp_acc[j] += gv;
          const float thr = (lg[j] > v3) ? v3 : v2;
          load_acc[j] += ndtr_f((cl[j] - thr) / sd[j]);
        }
      } else {
        if (l15 == 0) { const int idx = atomicAdd(flagcnt, 1); flaglist[idx] = (int)row; }
      }
    }
  }

  // ---- block-level reduction of load/imp/z, one atomic set per block ----
  #pragma unroll
  for (int j = 0; j < 4; ++j) {
    float L = load_acc[j]; L += __shfl_xor(L, 16, 64); L += __shfl_xor(L, 32, 64);
    float I = imp_acc[j];  I += __shfl_xor(I, 16, 64); I += __shfl_xor(I, 32, 64);
    if (l4 == 0) {
      red[wid * 64 + j * 16 + l15]       = L;
      red[256 + wid * 64 + j * 16 + l15] = I;
    }
  }
  {
    const float zw = sum64(z_acc);
    if (lane == 0) red[512 + wid] = zw;
  }
  __syncthreads();
  if (wid == 0) {
    const float L = red[lane] + red[64 + lane] + red[128 + lane] + red[192 + lane];
    const float I = red[256 + lane] + red[320 + lane] + red[384 + lane] + red[448 + lane];
    atomicAdd(&load_o[lane], L);
    atomicAdd(&imp_o[lane],  I);
    if (lane == 0) atomicAdd(zsum, red[512] + red[513] + red[514] + red[515]);
  }
}

// exact fp32 recompute of flagged rows, 4 rows per w-pass
__global__ __launch_bounds__(256) void fixup_k(
    const float* __restrict__ x, const float* __restrict__ wg, const float* __restrict__ wn,
    const float* __restrict__ eps,
    float* __restrict__ gates_buf, float* __restrict__ logits_buf,
    float* __restrict__ load_o, float* __restrict__ imp_o, float* __restrict__ zsum,
    const int* __restrict__ flagcnt, const int* __restrict__ flaglist)
{
  const int lane = threadIdx.x & 63;
  const int wid  = threadIdx.x >> 6;
  __shared__ float redg[4][4][64], redn[4][4][64];

  const int nf = *flagcnt;

  for (int it = blockIdx.x * 4; it < nf; it += gridDim.x * 4) {
    const int nr = (nf - it < 4) ? (nf - it) : 4;
    int rows[4];
    #pragma unroll
    for (int rr = 0; rr < 4; ++rr) rows[rr] = flaglist[it + ((rr < nr) ? rr : 0)];

    float dg[4] = {0.f,0.f,0.f,0.f}, dn[4] = {0.f,0.f,0.f,0.f};
    const int dbase = wid * 256;
    for (int d = 0; d < 256; d += 4) {
      const int db = (dbase + d) * E_EXP + lane;
      const float wgv0 = wg[db], wgv1 = wg[db + 64], wgv2 = wg[db + 128], wgv3 = wg[db + 192];
      const float wnv0 = wn[db], wnv1 = wn[db + 64], wnv2 = wn[db + 128], wnv3 = wn[db + 192];
      #pragma unroll
      for (int rr = 0; rr < 4; ++rr) {
        const float4 xv = *(const float4*)(x + (size_t)rows[rr] * D_DIM + dbase + d);
        dg[rr] = fmaf(xv.x, wgv0, dg[rr]);  dn[rr] = fmaf(xv.x, wnv0, dn[rr]);
        dg[rr] = fmaf(xv.y, wgv1, dg[rr]);  dn[rr] = fmaf(xv.y, wnv1, dn[rr]);
        dg[rr] = fmaf(xv.z, wgv2, dg[rr]);  dn[rr] = fmaf(xv.z, wnv2, dn[rr]);
        dg[rr] = fmaf(xv.w, wgv3, dg[rr]);  dn[rr] = fmaf(xv.w, wnv3, dn[rr]);
      }
    }
    #pragma unroll
    for (int rr = 0; rr < 4; ++rr) { redg[wid][rr][lane] = dg[rr]; redn[wid][rr][lane] = dn[rr]; }
    __syncthreads();
    if (wid < nr) {
      const int row = rows[wid];
      const float clean = redg[0][wid][lane] + redg[1][wid][lane] + redg[2][wid][lane] + redg[3][wid][lane];
      const float sdraw = redn[0][wid][lane] + redn[1][wid][lane] + redn[2][wid][lane] + redn[3][wid][lane];
      const float sd = softplus_f(sdraw) + 0.01f;
      const float ev = eps[(size_t)row * E_EXP + lane];
      const float l  = fmaf(ev, sd, clean);
      float la = 0.f, ia = 0.f, za = 0.f;
      row_epilogue_exact(row, lane, clean, sd, l, gates_buf, logits_buf, la, ia, za);
      atomicAdd(&load_o[lane], la);
      atomicAdd(&imp_o[lane],  ia);
      if (lane == 0) atomicAdd(zsum, za);
    }
    __syncthreads();
  }
}

__global__ void finalize_k(const float* __restrict__ load_o,
                           const float* __restrict__ imp_o,
                           const float* __restrict__ zsum,
                           float* __restrict__ out_lb) {
  const int e = threadIdx.x & 63;
  const double a = (double)load_o[e];
  const double b = (double)imp_o[e];
  double sl = a, sl2 = a * a, si = b, si2 = b * b;
  #pragma unroll
  for (int off = 32; off > 0; off >>= 1) {
    sl  += __shfl_xor(sl,  off, 64);
    sl2 += __shfl_xor(sl2, off, 64);
    si  += __shfl_xor(si,  off, 64);
    si2 += __shfl_xor(si2, off, 64);
  }
  if (e == 0) {
    const double n  = (double)E_EXP;
    const double ml = sl / n, mi = si / n;
    const double varl = (sl2 - n * ml * ml) / (n - 1.0);
    const double vari = (si2 - n * mi * mi) / (n - 1.0);
    const double cvl = varl / (ml * ml + 1e-10);
    const double cvi = vari / (mi * mi + 1e-10);
    const double z  = (double)zsum[0] / (double)B_ROWS;
    out_lb[0] = (float)(cvi + cvl + z);
  }
}

// ---------- launch ----------

extern "C" void kernel_launch(void* const* d_in, const int* in_sizes, int n_in,
                              void* d_out, int out_size, void* d_ws, size_t ws_size,
                              hipStream_t stream) {
  const float* x   = (const float*)d_in[0];
  const float* wg  = (const float*)d_in[1];
  const float* wn  = (const float*)d_in[2];
  const float* eps = (const float*)d_in[3];

  float* out    = (float*)d_out;
  float* gates  = out;                                       // [B*E]
  float* load_o = out + (size_t)B_ROWS * E_EXP;              // [E]
  float* logits = load_o + E_EXP;                            // [B*E]
  float* lb     = logits + (size_t)B_ROWS * E_EXP;           // [1]
  float* imp    = lb + 1;                                    // [E]

  // workspace: zsum @0, flagcnt @8, flaglist @256 (512KB), wt after
  float* zsum     = (float*)d_ws;
  int*   flagcnt  = (int*)d_ws + 2;
  int*   flaglist = (int*)((char*)d_ws + 256);
  f16*   wt       = (f16*)((char*)d_ws + 256 + 4 * (size_t)B_ROWS);

  prep_wt<<<32, 256, 0, stream>>>(wg, wn, wt, load_o, imp, zsum, flagcnt);
  gemm_fused<<<B_ROWS / 128, 256, 0, stream>>>(
      x, wt, eps, gates, logits, load_o, imp, zsum, flagcnt, flaglist);
  fixup_k<<<512, 256, 0, stream>>>(x, wg, wn, eps, gates, logits, load_o, imp, zsum, flagcnt, flaglist);
  finalize_k<<<1, 64, 0, stream>>>(load_o, imp, zsum, lb);
}

// Round 7
// 274.030 us; speedup vs baseline: 1.1349x; 1.1349x over previous
//
#include <hip/hip_runtime.h>
#include <math.h>

#define B_ROWS 131072
#define D_DIM  1024
#define E_EXP  64
#define MARGIN 4e-3f

typedef _Float16 f16;
typedef _Float16 f16x8 __attribute__((ext_vector_type(8)));
typedef float    f32x4 __attribute__((ext_vector_type(4)));

#define AS1C(p) ((const __attribute__((address_space(1))) void*)(p))
#define AS3(p)  ((__attribute__((address_space(3))) void*)(p))

// ---------- helpers ----------

__device__ __forceinline__ float softplus_f(float t) {
  return (t > 20.0f) ? t : log1pf(expf(t));
}
__device__ __forceinline__ float ndtr_f(float z) {
  return 0.5f * erfcf(-z * 0.70710678118654752f);
}
__device__ __forceinline__ void argmax64(float& v, int& vi) {
  #pragma unroll
  for (int off = 32; off > 0; off >>= 1) {
    float ov = __shfl_xor(v, off, 64);
    int   oi = __shfl_xor(vi, off, 64);
    if (ov > v || (ov == v && oi < vi)) { v = ov; vi = oi; }
  }
}
__device__ __forceinline__ float sum64(float v) {
  #pragma unroll
  for (int off = 32; off > 0; off >>= 1) v += __shfl_xor(v, off, 64);
  return v;
}

// full-64-lane (lane==expert) row epilogue, used by fixup only
__device__ __forceinline__ void row_epilogue_exact(
    int row, int lane, float clean, float sd, float l,
    float* __restrict__ gates_buf, float* __restrict__ logits_buf,
    float& load_acc, float& imp_acc, float& z_acc)
{
  float v1 = l; int i1 = lane; argmax64(v1, i1);
  float v2 = (lane == i1) ? -INFINITY : l; int i2 = lane; argmax64(v2, i2);
  float v3 = (lane == i1 || lane == i2) ? -INFINITY : l; int i3 = lane; argmax64(v3, i3);
  (void)i3;
  const float e21 = expf(v2 - v1);
  const float g1  = 1.0f / (1.0f + e21);
  const float g2  = e21 * g1;
  const float gv  = (lane == i1) ? g1 : ((lane == i2) ? g2 : 0.0f);
  gates_buf [(size_t)row * E_EXP + lane] = gv;
  logits_buf[(size_t)row * E_EXP + lane] = l;
  const float ssum = sum64(expf(l - v1));
  z_acc += v1 + logf(ssum);
  const float thr = (l > v3) ? v3 : v2;
  load_acc += ndtr_f((clean - thr) / sd);
  imp_acc  += gv;
}

// ---------- kernels ----------

// W^T f16 via coalesced LDS transpose; block 0 also zero-inits the accumulators.
__global__ __launch_bounds__(256) void prep_wt(
    const float* __restrict__ wg, const float* __restrict__ wn, f16* __restrict__ wt,
    float* load_o, float* imp_o, float* zsum, int* flagcnt) {
  if (blockIdx.x == 0) {
    const int t = threadIdx.x;
    if (t < 64) { load_o[t] = 0.0f; imp_o[t] = 0.0f; }
    if (t == 64) zsum[0] = 0.0f;
    if (t == 65) flagcnt[0] = 0;
  }
  __shared__ float tile[64][65];
  const int m  = blockIdx.x >> 4;       // 0 gate, 1 noise
  const int kt = blockIdx.x & 15;
  const int k0 = kt * 64;
  const float* src = m ? wn : wg;
  const int c = threadIdx.x & 63;
  const int r0 = threadIdx.x >> 6;
  #pragma unroll
  for (int r = r0; r < 64; r += 4)
    tile[r][c] = src[(size_t)(k0 + r) * 64 + c];   // coalesced read
  __syncthreads();
  const int j = threadIdx.x & 63;
  #pragma unroll
  for (int col = r0; col < 64; col += 4)
    wt[(size_t)(m * 64 + col) * 1024 + k0 + j] = (f16)tile[j][col];  // coalesced write
}

// Fused f16-MFMA GEMM + noisy-top-k epilogue.
// R5 structure (LDS-staged B via global_load_lds, double-buffered) but with
// COUNTED vmcnt barriers: the 8 A-prefetch HBM loads stay in flight across
// the barrier instead of being drained by __syncthreads' vmcnt(0).
// Block: 4 waves x 32 rows = 128 rows. Wave: 32 rows x 128 cols (64 gate + 64 noise).
__global__ __launch_bounds__(256, 3) void gemm_fused(
    const float* __restrict__ x, const f16* __restrict__ wt,
    const float* __restrict__ eps,
    float* __restrict__ gates_buf, float* __restrict__ logits_buf,
    float* __restrict__ load_o, float* __restrict__ imp_o, float* __restrict__ zsum,
    int* __restrict__ flagcnt, int* __restrict__ flaglist)
{
  __shared__ __align__(16) char wlds[2][16384];   // [buf][128 cols x 64 k x f16]

  const int tid  = threadIdx.x;
  const int lane = tid & 63;
  const int wid  = tid >> 6;
  const int l15  = lane & 15;
  const int l4   = lane >> 4;
  const size_t rowbase = (size_t)blockIdx.x * 128 + wid * 32;

  // ---- B staging via global_load_lds: linear LDS dest, pre-swizzled global src ----
  // col c lives at LDS byte c*128; k-element-block j at byte (j<<4)^((c&7)<<4).
  const int scol0 = wid * 8 + (lane >> 3);
  const int skel  = ((lane & 7) * 8) ^ ((lane >> 3) << 3);
  const f16* wsrc0 = wt + (size_t)(scol0 +  0) * 1024 + skel;
  const f16* wsrc1 = wt + (size_t)(scol0 + 32) * 1024 + skel;
  const f16* wsrc2 = wt + (size_t)(scol0 + 64) * 1024 + skel;
  const f16* wsrc3 = wt + (size_t)(scol0 + 96) * 1024 + skel;

#define ISSUE_B(buf, kc) do {                                                                      \
    __builtin_amdgcn_global_load_lds(AS1C(wsrc0 + (kc) * 64), AS3(&wlds[buf][0*4096 + wid*1024]), 16, 0, 0); \
    __builtin_amdgcn_global_load_lds(AS1C(wsrc1 + (kc) * 64), AS3(&wlds[buf][1*4096 + wid*1024]), 16, 0, 0); \
    __builtin_amdgcn_global_load_lds(AS1C(wsrc2 + (kc) * 64), AS3(&wlds[buf][2*4096 + wid*1024]), 16, 0, 0); \
    __builtin_amdgcn_global_load_lds(AS1C(wsrc3 + (kc) * 64), AS3(&wlds[buf][3*4096 + wid*1024]), 16, 0, 0); \
  } while (0)

  // counted-vmcnt barrier: wave's 4 B-DMA loads (older) are retired when <=8
  // VMEM ops remain; the 8 A-prefetch loads (newer) keep streaming across.
#define PIPE_BARRIER() do {                                  \
    asm volatile("s_waitcnt vmcnt(8)" ::: "memory");         \
    __builtin_amdgcn_s_barrier();                            \
    __builtin_amdgcn_sched_barrier(0);                       \
  } while (0)

  // ---- A pointers: lane covers rows (rowbase + rt*16 + l15), k = l4*8.. ----
  const float* xp0 = x + (rowbase +  0 + l15) * D_DIM + l4 * 8;
  const float* xp1 = x + (rowbase + 16 + l15) * D_DIM + l4 * 8;

  f32x4 acc[2][8];
  #pragma unroll
  for (int rt = 0; rt < 2; ++rt)
    #pragma unroll
    for (int et = 0; et < 8; ++et) acc[rt][et] = (f32x4)0.0f;

  float4 xa[8];   // xa[kl*4 + rt*2 + h]
#define LOAD_A(kc) do {                                                  \
    _Pragma("unroll")                                                    \
    for (int kl = 0; kl < 2; ++kl) {                                     \
      xa[kl*4 + 0] = *(const float4*)(xp0 + (kc)*64 + kl*32 + 0);        \
      xa[kl*4 + 1] = *(const float4*)(xp0 + (kc)*64 + kl*32 + 4);        \
      xa[kl*4 + 2] = *(const float4*)(xp1 + (kc)*64 + kl*32 + 0);        \
      xa[kl*4 + 3] = *(const float4*)(xp1 + (kc)*64 + kl*32 + 4);        \
    }                                                                    \
  } while (0)

  // prologue
  ISSUE_B(0, 0);
  LOAD_A(0);
  PIPE_BARRIER();

  #pragma unroll 1
  for (int kc = 0; kc < 16; ++kc) {
    const int buf = kc & 1;

    // issue next B DMA first (no register dest -> cheap, oldest in queue)
    if (kc < 15) ISSUE_B(buf ^ 1, kc + 1);

    // convert A(kc) -> f16 frags (compiler waits only the A loads; B-next stays in flight)
    f16x8 af[2][2];   // [kl][rt]
    #pragma unroll
    for (int kl = 0; kl < 2; ++kl)
      #pragma unroll
      for (int rt = 0; rt < 2; ++rt) {
        #pragma unroll
        for (int h = 0; h < 2; ++h) {
          const float4 v = xa[kl*4 + rt*2 + h];
          af[kl][rt][h*4 + 0] = (f16)v.x;
          af[kl][rt][h*4 + 1] = (f16)v.y;
          af[kl][rt][h*4 + 2] = (f16)v.z;
          af[kl][rt][h*4 + 3] = (f16)v.w;
        }
      }

    // prefetch next chunk's A (the HBM stream — keep it always in flight)
    if (kc < 15) LOAD_A(kc + 1);

    // MFMA: 2 kl x 8 et x 2 rt
    #pragma unroll
    for (int kl = 0; kl < 2; ++kl) {
      #pragma unroll
      for (int et = 0; et < 8; ++et) {
        const int bcol = et * 16 + l15;
        const int boff = (bcol * 128 + kl * 64 + l4 * 16) ^ ((l15 & 7) << 4);
        const f16x8 b = *(const f16x8*)(&wlds[buf][boff]);
        acc[0][et] = __builtin_amdgcn_mfma_f32_16x16x32_f16(af[kl][0], b, acc[0][et], 0, 0, 0);
        acc[1][et] = __builtin_amdgcn_mfma_f32_16x16x32_f16(af[kl][1], b, acc[1][et], 0, 0, 0);
      }
    }

    // publish LDS[buf^1]; A(kc+1) loads keep flying across the barrier
    if (kc < 15) PIPE_BARRIER();
  }
#undef ISSUE_B
#undef LOAD_A
#undef PIPE_BARRIER

  // ---- fused epilogue: acc[rt][0..3] = clean, acc[rt][4..7] = sdraw ----
  float load_acc[4] = {0.f, 0.f, 0.f, 0.f};
  float imp_acc[4]  = {0.f, 0.f, 0.f, 0.f};
  float z_acc = 0.f;

  #pragma unroll
  for (int rt = 0; rt < 2; ++rt) {
    #pragma unroll
    for (int rg = 0; rg < 4; ++rg) {
      const size_t row = rowbase + rt * 16 + l4 * 4 + rg;
      float cl[4], sd[4], lg[4];
      #pragma unroll
      for (int j = 0; j < 4; ++j) {
        cl[j] = acc[rt][j][rg];
        sd[j] = softplus_f(acc[rt][4 + j][rg]) + 0.01f;
        const float ev = eps[row * E_EXP + j * 16 + l15];
        lg[j] = fmaf(ev, sd[j], cl[j]);
      }
      // top-1 over the row (16 lanes x 4 local)
      float v = lg[0]; int c = l15;
      #pragma unroll
      for (int j = 1; j < 4; ++j) {
        const int cj = j * 16 + l15;
        if (lg[j] > v || (lg[j] == v && cj < c)) { v = lg[j]; c = cj; }
      }
      #pragma unroll
      for (int off = 1; off < 16; off <<= 1) {
        const float ov = __shfl_xor(v, off, 64);
        const int   oc = __shfl_xor(c, off, 64);
        if (ov > v || (ov == v && oc < c)) { v = ov; c = oc; }
      }
      const float v1 = v; const int i1 = c;
      // top-2
      v = -INFINITY; c = 1 << 30;
      #pragma unroll
      for (int j = 0; j < 4; ++j) {
        const int cj = j * 16 + l15;
        if (cj != i1 && (lg[j] > v || (lg[j] == v && cj < c))) { v = lg[j]; c = cj; }
      }
      #pragma unroll
      for (int off = 1; off < 16; off <<= 1) {
        const float ov = __shfl_xor(v, off, 64);
        const int   oc = __shfl_xor(c, off, 64);
        if (ov > v || (ov == v && oc < c)) { v = ov; c = oc; }
      }
      const float v2 = v; const int i2 = c;
      // top-3 (value only)
      float v3 = -INFINITY;
      #pragma unroll
      for (int j = 0; j < 4; ++j) {
        const int cj = j * 16 + l15;
        if (cj != i1 && cj != i2) v3 = fmaxf(v3, lg[j]);
      }
      #pragma unroll
      for (int off = 1; off < 16; off <<= 1) v3 = fmaxf(v3, __shfl_xor(v3, off, 64));

      if (v2 - v3 >= MARGIN) {
        const float e21 = expf(v2 - v1);
        const float g1  = 1.0f / (1.0f + e21);
        const float g2  = e21 * g1;
        float s = 0.f;
        #pragma unroll
        for (int j = 0; j < 4; ++j) s += expf(lg[j] - v1);
        #pragma unroll
        for (int off = 1; off < 16; off <<= 1) s += __shfl_xor(s, off, 64);
        if (l15 == 0) z_acc += v1 + logf(s);
        #pragma unroll
        for (int j = 0; j < 4; ++j) {
          const int cj = j * 16 + l15;
          const float gv = (cj == i1) ? g1 : ((cj == i2) ? g2 : 0.0f);
          gates_buf [row * E_EXP + cj] = gv;
          logits_buf[row * E_EXP + cj] = lg[j];
          imp_acc[j] += gv;
          const float thr = (lg[j] > v3) ? v3 : v2;
          load_acc[j] += ndtr_f((cl[j] - thr) / sd[j]);
        }
      } else {
        if (l15 == 0) { const int idx = atomicAdd(flagcnt, 1); flaglist[idx] = (int)row; }
      }
    }
  }

  // ---- block-level reduction of load/imp/z, one atomic set per block ----
  // (reuses wlds[0] region; kc=15 computed on wlds[1], so no read hazard)
  float* red = (float*)&wlds[0][0];
  #pragma unroll
  for (int j = 0; j < 4; ++j) {
    float L = load_acc[j]; L += __shfl_xor(L, 16, 64); L += __shfl_xor(L, 32, 64);
    float I = imp_acc[j];  I += __shfl_xor(I, 16, 64); I += __shfl_xor(I, 32, 64);
    if (l4 == 0) {
      red[wid * 64 + j * 16 + l15]       = L;
      red[256 + wid * 64 + j * 16 + l15] = I;
    }
  }
  {
    const float zw = sum64(z_acc);
    if (lane == 0) red[512 + wid] = zw;
  }
  __syncthreads();
  if (wid == 0) {
    const float L = red[lane] + red[64 + lane] + red[128 + lane] + red[192 + lane];
    const float I = red[256 + lane] + red[320 + lane] + red[384 + lane] + red[448 + lane];
    atomicAdd(&load_o[lane], L);
    atomicAdd(&imp_o[lane],  I);
    if (lane == 0) atomicAdd(zsum, red[512] + red[513] + red[514] + red[515]);
  }
}

// exact fp32 recompute of flagged rows, 4 rows per w-pass
__global__ __launch_bounds__(256) void fixup_k(
    const float* __restrict__ x, const float* __restrict__ wg, const float* __restrict__ wn,
    const float* __restrict__ eps,
    float* __restrict__ gates_buf, float* __restrict__ logits_buf,
    float* __restrict__ load_o, float* __restrict__ imp_o, float* __restrict__ zsum,
    const int* __restrict__ flagcnt, const int* __restrict__ flaglist)
{
  const int lane = threadIdx.x & 63;
  const int wid  = threadIdx.x >> 6;
  __shared__ float redg[4][4][64], redn[4][4][64];

  const int nf = *flagcnt;

  for (int it = blockIdx.x * 4; it < nf; it += gridDim.x * 4) {
    const int nr = (nf - it < 4) ? (nf - it) : 4;
    int rows[4];
    #pragma unroll
    for (int rr = 0; rr < 4; ++rr) rows[rr] = flaglist[it + ((rr < nr) ? rr : 0)];

    float dg[4] = {0.f,0.f,0.f,0.f}, dn[4] = {0.f,0.f,0.f,0.f};
    const int dbase = wid * 256;
    for (int d = 0; d < 256; d += 4) {
      const int db = (dbase + d) * E_EXP + lane;
      const float wgv0 = wg[db], wgv1 = wg[db + 64], wgv2 = wg[db + 128], wgv3 = wg[db + 192];
      const float wnv0 = wn[db], wnv1 = wn[db + 64], wnv2 = wn[db + 128], wnv3 = wn[db + 192];
      #pragma unroll
      for (int rr = 0; rr < 4; ++rr) {
        const float4 xv = *(const float4*)(x + (size_t)rows[rr] * D_DIM + dbase + d);
        dg[rr] = fmaf(xv.x, wgv0, dg[rr]);  dn[rr] = fmaf(xv.x, wnv0, dn[rr]);
        dg[rr] = fmaf(xv.y, wgv1, dg[rr]);  dn[rr] = fmaf(xv.y, wnv1, dn[rr]);
        dg[rr] = fmaf(xv.z, wgv2, dg[rr]);  dn[rr] = fmaf(xv.z, wnv2, dn[rr]);
        dg[rr] = fmaf(xv.w, wgv3, dg[rr]);  dn[rr] = fmaf(xv.w, wnv3, dn[rr]);
      }
    }
    #pragma unroll
    for (int rr = 0; rr < 4; ++rr) { redg[wid][rr][lane] = dg[rr]; redn[wid][rr][lane] = dn[rr]; }
    __syncthreads();
    if (wid < nr) {
      const int row = rows[wid];
      const float clean = redg[0][wid][lane] + redg[1][wid][lane] + redg[2][wid][lane] + redg[3][wid][lane];
      const float sdraw = redn[0][wid][lane] + redn[1][wid][lane] + redn[2][wid][lane] + redn[3][wid][lane];
      const float sd = softplus_f(sdraw) + 0.01f;
      const float ev = eps[(size_t)row * E_EXP + lane];
      const float l  = fmaf(ev, sd, clean);
      float la = 0.f, ia = 0.f, za = 0.f;
      row_epilogue_exact(row, lane, clean, sd, l, gates_buf, logits_buf, la, ia, za);
      atomicAdd(&load_o[lane], la);
      atomicAdd(&imp_o[lane],  ia);
      if (lane == 0) atomicAdd(zsum, za);
    }
    __syncthreads();
  }
}

__global__ void finalize_k(const float* __restrict__ load_o,
                           const float* __restrict__ imp_o,
                           const float* __restrict__ zsum,
                           float* __restrict__ out_lb) {
  const int e = threadIdx.x & 63;
  const double a = (double)load_o[e];
  const double b = (double)imp_o[e];
  double sl = a, sl2 = a * a, si = b, si2 = b * b;
  #pragma unroll
  for (int off = 32; off > 0; off >>= 1) {
    sl  += __shfl_xor(sl,  off, 64);
    sl2 += __shfl_xor(sl2, off, 64);
    si  += __shfl_xor(si,  off, 64);
    si2 += __shfl_xor(si2, off, 64);
  }
  if (e == 0) {
    const double n  = (double)E_EXP;
    const double ml = sl / n, mi = si / n;
    const double varl = (sl2 - n * ml * ml) / (n - 1.0);
    const double vari = (si2 - n * mi * mi) / (n - 1.0);
    const double cvl = varl / (ml * ml + 1e-10);
    const double cvi = vari / (mi * mi + 1e-10);
    const double z  = (double)zsum[0] / (double)B_ROWS;
    out_lb[0] = (float)(cvi + cvl + z);
  }
}

// ---------- launch ----------

extern "C" void kernel_launch(void* const* d_in, const int* in_sizes, int n_in,
                              void* d_out, int out_size, void* d_ws, size_t ws_size,
                              hipStream_t stream) {
  const float* x   = (const float*)d_in[0];
  const float* wg  = (const float*)d_in[1];
  const float* wn  = (const float*)d_in[2];
  const float* eps = (const float*)d_in[3];

  float* out    = (float*)d_out;
  float* gates  = out;                                       // [B*E]
  float* load_o = out + (size_t)B_ROWS * E_EXP;              // [E]
  float* logits = load_o + E_EXP;                            // [B*E]
  float* lb     = logits + (size_t)B_ROWS * E_EXP;           // [1]
  float* imp    = lb + 1;                                    // [E]

  // workspace: zsum @0, flagcnt @8, flaglist @256 (512KB), wt after
  float* zsum     = (float*)d_ws;
  int*   flagcnt  = (int*)d_ws + 2;
  int*   flaglist = (int*)((char*)d_ws + 256);
  f16*   wt       = (f16*)((char*)d_ws + 256 + 4 * (size_t)B_ROWS);

  prep_wt<<<32, 256, 0, stream>>>(wg, wn, wt, load_o, imp, zsum, flagcnt);
  gemm_fused<<<B_ROWS / 128, 256, 0, stream>>>(
      x, wt, eps, gates, logits, load_o, imp, zsum, flagcnt, flaglist);
  fixup_k<<<512, 256, 0, stream>>>(x, wg, wn, eps, gates, logits, load_o, imp, zsum, flagcnt, flaglist);
  finalize_k<<<1, 64, 0, stream>>>(load_o, imp, zsum, lb);
}